// Round 6
// baseline (197.914 us; speedup 1.0000x reference)
//
#include <hip/hip_runtime.h>

// N=8192, d_model=2048, h=16, d_k=128.
// softmax over a size-1 axis == 1.0 exactly -> head_out[h,n,:] = v_proj[h,0,:].
// out[n][m] = r[m],  r = vp @ Wo,  vp[h*128+k] = sum_d v_param[d]*Wv[h,d,k].
//
// SINGLE kernel (graph-capturable), 512 blocks x 256 thr, software grid barrier:
//  Phase A: Wv (16 MB) -> part1[32][2048] vp-partials; blocks 0..7 zero r.
//  bar1
//  Phase B: stage vp slice (L2), GEMV partial vs Wo (16 MB, read exactly once),
//           atomicAdd into r (8 adds/address).
//  bar2
//  Phase C: broadcast r to 16 rows/block, float4 stores (64 MB).
//
// Barrier counters live in ws and are self-sanitizing across graph replays:
// entry CAS(poison->0) and CAS(GRID->0); counters only reach GRID after every
// block has already CAS'ed (CAS precedes arrival). Bounded spin avoids wedge.

#define DM     2048
#define H      16
#define DK     128
#define GRID   512
#define GOAL   512u
#define POISON 0xAAAAAAAAu

__device__ __forceinline__ void gridbar(unsigned int* cnt) {
    __syncthreads();                       // drain block's stores (vmcnt 0)
    if (threadIdx.x == 0) {
        __threadfence();                   // release: L2 writeback (agent scope)
        atomicAdd(cnt, 1u);
        unsigned v; int it = 0;
        do {
            v = __hip_atomic_load(cnt, __ATOMIC_ACQUIRE, __HIP_MEMORY_SCOPE_AGENT);
            if (v >= GOAL) break;
            __builtin_amdgcn_s_sleep(4);
        } while (++it < (1 << 22));
    }
    __syncthreads();
    __threadfence();                       // acquire: invalidate L1/L2
}

__global__ __launch_bounds__(256, 4) void fused_mha(
    const float* __restrict__ Wv,
    const float* __restrict__ vparam,
    const float* __restrict__ Wo,
    float* __restrict__ out,
    float* __restrict__ part1,     // [32][2048] floats (256 KB)
    float* __restrict__ r,         // [2048] floats
    unsigned int* __restrict__ cnt) // [2]
{
    const int b = blockIdx.x;
    const int t = threadIdx.x;

    // sanitize barrier counters (poison on first launch, GOAL afterwards)
    if (t == 0) {
        atomicCAS(&cnt[0], POISON, 0u);
        atomicCAS(&cnt[0], GOAL,   0u);
        atomicCAS(&cnt[1], POISON, 0u);
        atomicCAS(&cnt[1], GOAL,   0u);
    }

    // ---- Phase A: Wv partial v-projection ----
    const int h    = b & 15;
    const int dseg = b >> 4;            // 0..31 (64 d's per block)
    const int k    = t & 127;
    const int dh   = t >> 7;            // 0..1  (32 d's per thread)
    const int d0   = dseg * 64 + dh * 32;
    const float* wp = Wv + ((size_t)h * DM + d0) * DK + k;
    float acc = 0.f;
#pragma unroll
    for (int i = 0; i < 32; ++i) acc += vparam[d0 + i] * wp[(size_t)i * DK];
    __shared__ float ared[128];
    if (dh == 1) ared[k] = acc;
    __syncthreads();
    if (dh == 0) part1[(size_t)dseg * DM + h * DK + k] = acc + ared[k];

    if (b < 8) r[(b << 8) + t] = 0.f;   // zero accumulator before any atomics

    gridbar(&cnt[0]);

    // ---- Phase B: vp slice + GEMV partial ----
    const int ms = b & 63;              // 0..63: cols ms*32 .. +32
    const int jq = b >> 6;              // 0..7 : j's  jq*256 .. +256
    __shared__ float vp_s[256];
    {
        float s = 0.f;
        const float* p = part1 + jq * 256 + t;
#pragma unroll 8
        for (int c = 0; c < 32; ++c) s += p[(size_t)c * DM];
        vp_s[t] = s;
    }
    __syncthreads();
    {
        const int c  = t & 31;
        const int jg = t >> 5;          // 0..7 (8 j-groups of 32)
        const float* wo = Wo + (size_t)(jq * 256 + jg * 32) * DM + ms * 32 + c;
        float a2 = 0.f;
#pragma unroll 8
        for (int i = 0; i < 32; ++i) a2 += vp_s[jg * 32 + i] * wo[(size_t)i * DM];
        __shared__ float red[8][33];
        red[jg][c] = a2;
        __syncthreads();
        if (t < 32) {
            float s = 0.f;
#pragma unroll
            for (int g = 0; g < 8; ++g) s += red[g][t];
            atomicAdd(&r[ms * 32 + t], s);
        }
    }

    gridbar(&cnt[1]);

    // ---- Phase C: broadcast r to 16 output rows ----
    const float4 v0 = ((const float4*)r)[t];
    const float4 v1 = ((const float4*)r)[256 + t];
    float4* o4 = (float4*)out + (size_t)b * 16 * (DM / 4);
#pragma unroll
    for (int n = 0; n < 16; ++n) {
        o4[(size_t)n * (DM / 4) + t]       = v0;
        o4[(size_t)n * (DM / 4) + 256 + t] = v1;
    }
}

extern "C" void kernel_launch(void* const* d_in, const int* in_sizes, int n_in,
                              void* d_out, int out_size, void* d_ws, size_t ws_size,
                              hipStream_t stream) {
    // inputs: 0=q, 1=Wq, 2=Wk, 3=Wv, 4=k_param, 5=v_param, 6=Wo (all fp32)
    const float* Wv     = (const float*)d_in[3];
    const float* vparam = (const float*)d_in[5];
    const float* Wo     = (const float*)d_in[6];
    float* out = (float*)d_out;

    float* part1      = (float*)d_ws;         // 32*2048 floats = 256 KB
    float* r          = part1 + 32 * DM;      // 2048 floats
    unsigned int* cnt = (unsigned int*)(r + DM); // 2 uints

    fused_mha<<<GRID, 256, 0, stream>>>(Wv, vparam, Wo, out, part1, r, cnt);
}

// Round 7
// 116.189 us; speedup vs baseline: 1.7034x; 1.7034x over previous
//
#include <hip/hip_runtime.h>

// N=8192, d_model=2048, h=16, d_k=128.
// softmax over a size-1 axis == 1.0 exactly -> head_out[h,n,:] = v_proj[h,0,:].
// out[n][m] = r[m],  r = vp @ Wo,  vp[h*128+k] = sum_d v_param[d]*Wv[h,d,k].
//
// SINGLE kernel, 512 blocks x 256 thr, software grid barrier:
//  Phase A: Wv (16 MB) -> part1[32][2048] vp-partials; blocks 0..7 zero r.
//  bar1
//  Phase B: stage vp slice, GEMV partial vs Wo (16 MB, read exactly once),
//           atomicAdd into r.
//  bar2
//  Phase C: broadcast r to 16 rows/block, float4 stores (64 MB).
//
// Barrier: RELAXED agent-scope poll (sc1 load, NO per-poll invalidate — R6's
// ACQUIRE-poll was an L2-inv storm that cost 170 us), one release fence before
// arrival, one wb+inv fence by t0 after exit. Counters self-sanitize across
// graph replays via entry CAS (poison->0, GOAL->0); every CAS precedes every
// arrival, and cnt reaches GOAL only after all blocks CAS'ed. Bounded spin.

#define DM     2048
#define H      16
#define DK     128
#define GRID   512
#define GOAL   512u
#define POISON 0xAAAAAAAAu

__device__ __forceinline__ void gridbar(unsigned int* cnt) {
    __syncthreads();                       // all block stores issued & drained
    if (threadIdx.x == 0) {
        __threadfence();                   // release: wb L2 to coherence point
        atomicAdd(cnt, 1u);
        unsigned v; int it = 0;
        do {
            v = __hip_atomic_load(cnt, __ATOMIC_RELAXED, __HIP_MEMORY_SCOPE_AGENT);
            if (v >= GOAL) break;
            __builtin_amdgcn_s_sleep(8);
        } while (++it < (1 << 22));
        __threadfence();                   // acquire: inv L1/L2 once, pre-read
    }
    __syncthreads();                       // others' loads ordered after inv
}

__global__ __launch_bounds__(256, 4) void fused_mha(
    const float* __restrict__ Wv,
    const float* __restrict__ vparam,
    const float* __restrict__ Wo,
    float* __restrict__ out,
    float* __restrict__ part1,      // [32][2048] floats (256 KB)
    float* __restrict__ r,          // [2048] floats
    unsigned int* __restrict__ cnt) // [2]
{
    const int b = blockIdx.x;
    const int t = threadIdx.x;

    // sanitize barrier counters (poison on first launch, GOAL afterwards)
    if (t == 0) {
        atomicCAS(&cnt[0], POISON, 0u);
        atomicCAS(&cnt[0], GOAL,   0u);
        atomicCAS(&cnt[1], POISON, 0u);
        atomicCAS(&cnt[1], GOAL,   0u);
    }

    // ---- Phase A: Wv partial v-projection ----
    const int h    = b & 15;
    const int dseg = b >> 4;            // 0..31 (64 d's per block)
    const int k    = t & 127;
    const int dh   = t >> 7;            // 0..1  (32 d's per thread)
    const int d0   = dseg * 64 + dh * 32;
    const float* wp = Wv + ((size_t)h * DM + d0) * DK + k;
    float acc = 0.f;
#pragma unroll
    for (int i = 0; i < 32; ++i) acc += vparam[d0 + i] * wp[(size_t)i * DK];
    __shared__ float ared[128];
    if (dh == 1) ared[k] = acc;
    __syncthreads();
    if (dh == 0) part1[(size_t)dseg * DM + h * DK + k] = acc + ared[k];

    if (b < 8) r[(b << 8) + t] = 0.f;   // zero accumulator before any atomics

    gridbar(&cnt[0]);

    // ---- Phase B: vp slice + GEMV partial ----
    const int ms = b & 63;              // 0..63: cols ms*32 .. +32
    const int jq = b >> 6;              // 0..7 : j's  jq*256 .. +256
    __shared__ float vp_s[256];
    {
        float s = 0.f;
        const float* p = part1 + jq * 256 + t;
#pragma unroll 8
        for (int c = 0; c < 32; ++c) s += p[(size_t)c * DM];
        vp_s[t] = s;
    }
    __syncthreads();
    {
        const int c  = t & 31;
        const int jg = t >> 5;          // 0..7 (8 j-groups of 32)
        const float* wo = Wo + (size_t)(jq * 256 + jg * 32) * DM + ms * 32 + c;
        float a2 = 0.f;
#pragma unroll 8
        for (int i = 0; i < 32; ++i) a2 += vp_s[jg * 32 + i] * wo[(size_t)i * DM];
        __shared__ float red[8][33];
        red[jg][c] = a2;
        __syncthreads();
        if (t < 32) {
            float s = 0.f;
#pragma unroll
            for (int g = 0; g < 8; ++g) s += red[g][t];
            atomicAdd(&r[ms * 32 + t], s);
        }
    }

    gridbar(&cnt[1]);

    // ---- Phase C: broadcast r to 16 output rows ----
    const float4 v0 = ((const float4*)r)[t];
    const float4 v1 = ((const float4*)r)[256 + t];
    float4* o4 = (float4*)out + (size_t)b * 16 * (DM / 4);
#pragma unroll
    for (int n = 0; n < 16; ++n) {
        o4[(size_t)n * (DM / 4) + t]       = v0;
        o4[(size_t)n * (DM / 4) + 256 + t] = v1;
    }
}

extern "C" void kernel_launch(void* const* d_in, const int* in_sizes, int n_in,
                              void* d_out, int out_size, void* d_ws, size_t ws_size,
                              hipStream_t stream) {
    // inputs: 0=q, 1=Wq, 2=Wk, 3=Wv, 4=k_param, 5=v_param, 6=Wo (all fp32)
    const float* Wv     = (const float*)d_in[3];
    const float* vparam = (const float*)d_in[5];
    const float* Wo     = (const float*)d_in[6];
    float* out = (float*)d_out;

    float* part1      = (float*)d_ws;            // 32*2048 floats = 256 KB
    float* r          = part1 + 32 * DM;         // 2048 floats
    unsigned int* cnt = (unsigned int*)(r + DM); // 2 uints

    fused_mha<<<GRID, 256, 0, stream>>>(Wv, vparam, Wo, out, part1, r, cnt);
}

// Round 8
// 62.325 us; speedup vs baseline: 3.1755x; 1.8642x over previous
//
#include <hip/hip_runtime.h>

// N=8192, d_model=2048, h=16, d_k=128.
// softmax over a size-1 axis == 1.0 exactly -> head_out[h,n,:] = v_proj[h,0,:].
// out[n][m] = r[m],  r = vp @ Wo,  vp[h*128+k] = sum_d v_param[d]*Wv[h,d,k].
//
// SINGLE kernel, 512 blocks x 256 thr, fence-free software grid barrier:
//  - all cross-block data (part1, r) moves via agent-scope RELAXED atomic
//    load/store = sc1 write-through/L2-bypass, coherent at Infinity Cache.
//    NO __threadfence (R6/R7 spent ~100us on per-block/per-poll L2 wb/inv).
//  - barrier poll is an atomic RMW fetch_add(cnt,0): executes at the
//    coherence point, always fresh, no invalidates.
//  - __syncthreads() before arrival drains vmcnt (compiler emits
//    s_waitcnt vmcnt(0) before s_barrier), so write-through stores are
//    visible before the arrival add.
//  Phase A: Wv (16 MB) -> part1 vp-partials; Wo slice -> 32 regs (prefetch,
//           overlaps the two 16 MB reads); blocks 0..7 zero r.
//  bar1
//  Phase B: vp slice from part1 (IC), dot with reg-staged Wo, one
//           atomicAdd per (block, r-elem).
//  bar2
//  Phase C: broadcast r to 16 rows/block, float4 stores (64 MB).
//
// cnt self-sanitizes across graph replays: CAS(poison->0), CAS(GOAL->0);
// every CAS precedes every arrival. Bounded spin converts residency
// failure into fast wrong-answer instead of a hang.

#define DM     2048
#define H      16
#define DK     128
#define GRID   512
#define GOAL   512u
#define POISON 0xAAAAAAAAu

__device__ __forceinline__ float ld_coh(const float* p) {
    return __hip_atomic_load(p, __ATOMIC_RELAXED, __HIP_MEMORY_SCOPE_AGENT);
}
__device__ __forceinline__ void st_coh(float* p, float v) {
    __hip_atomic_store(p, v, __ATOMIC_RELAXED, __HIP_MEMORY_SCOPE_AGENT);
}

__device__ __forceinline__ void gridbar(unsigned int* cnt) {
    __syncthreads();                  // drains vmcnt: wt-stores visible at IC
    if (threadIdx.x == 0) {
        __hip_atomic_fetch_add(cnt, 1u, __ATOMIC_RELAXED, __HIP_MEMORY_SCOPE_AGENT);
        int it = 0;
        do {
            unsigned v = __hip_atomic_fetch_add(cnt, 0u, __ATOMIC_RELAXED,
                                                __HIP_MEMORY_SCOPE_AGENT);
            if (v >= GOAL) break;
            __builtin_amdgcn_s_sleep(32);
        } while (++it < (1 << 18));
    }
    __syncthreads();
}

__global__ __launch_bounds__(256, 4) void fused_mha(
    const float* __restrict__ Wv,
    const float* __restrict__ vparam,
    const float* __restrict__ Wo,
    float* __restrict__ out,
    float* __restrict__ part1,      // [32][2048] floats (256 KB)
    float* __restrict__ r,          // [2048] floats
    unsigned int* __restrict__ cnt) // [2]
{
    const int b = blockIdx.x;
    const int t = threadIdx.x;

    // sanitize barrier counters (poison on first launch, GOAL on replays)
    if (t == 0) {
        atomicCAS(&cnt[0], POISON, 0u);
        atomicCAS(&cnt[0], GOAL,   0u);
        atomicCAS(&cnt[1], POISON, 0u);
        atomicCAS(&cnt[1], GOAL,   0u);
    }

    // ---- Phase B prefetch: this block's Wo slice -> 32 registers ----
    const int ms = b & 63;              // 0..63: cols ms*32 .. +32
    const int jq = b >> 6;              // 0..7 : j's  jq*256 .. +256
    const int c  = t & 31;              // col within slice
    const int jg = t >> 5;              // 0..7: j-group of 32
    float wo_reg[32];
    {
        const float* wop = Wo + (size_t)(jq * 256 + jg * 32) * DM + ms * 32 + c;
#pragma unroll
        for (int i = 0; i < 32; ++i) wo_reg[i] = wop[(size_t)i * DM];
    }

    // ---- Phase A: Wv partial v-projection ----
    const int h    = b & 15;
    const int dseg = b >> 4;            // 0..31 (64 d's per block)
    const int k    = t & 127;
    const int dh   = t >> 7;            // 0..1  (32 d's per thread)
    const int d0   = dseg * 64 + dh * 32;
    {
        const float* wp = Wv + ((size_t)h * DM + d0) * DK + k;
        float acc = 0.f;
#pragma unroll
        for (int i = 0; i < 32; ++i) acc += vparam[d0 + i] * wp[(size_t)i * DK];
        __shared__ float ared[128];
        if (dh == 1) ared[k] = acc;
        __syncthreads();
        if (dh == 0) st_coh(&part1[(size_t)dseg * DM + h * DK + k], acc + ared[k]);
    }

    if (b < 8) st_coh(&r[(b << 8) + t], 0.f);   // zero accumulator pre-bar1

    gridbar(&cnt[0]);

    // ---- Phase B: vp slice from part1 (IC-coherent), dot with wo_reg ----
    __shared__ float vp_s[256];
    {
        float s = 0.f;
        const float* p = part1 + jq * 256 + t;
#pragma unroll 8
        for (int cc = 0; cc < 32; ++cc) s += ld_coh(&p[(size_t)cc * DM]);
        vp_s[t] = s;
    }
    __syncthreads();
    {
        float a2 = 0.f;
#pragma unroll
        for (int i = 0; i < 32; ++i) a2 += vp_s[jg * 32 + i] * wo_reg[i];
        __shared__ float red[8][33];
        red[jg][c] = a2;
        __syncthreads();
        if (t < 32) {
            float s = 0.f;
#pragma unroll
            for (int g = 0; g < 8; ++g) s += red[g][t];
            atomicAdd(&r[ms * 32 + t], s);
        }
    }

    gridbar(&cnt[1]);

    // ---- Phase C: broadcast r (IC-coherent reads) to 16 output rows ----
    float4 v0, v1;
    v0.x = ld_coh(&r[4 * t + 0]);        v0.y = ld_coh(&r[4 * t + 1]);
    v0.z = ld_coh(&r[4 * t + 2]);        v0.w = ld_coh(&r[4 * t + 3]);
    v1.x = ld_coh(&r[1024 + 4 * t + 0]); v1.y = ld_coh(&r[1024 + 4 * t + 1]);
    v1.z = ld_coh(&r[1024 + 4 * t + 2]); v1.w = ld_coh(&r[1024 + 4 * t + 3]);
    float4* o4 = (float4*)out + (size_t)b * 16 * (DM / 4);
#pragma unroll
    for (int n = 0; n < 16; ++n) {
        o4[(size_t)n * (DM / 4) + t]       = v0;
        o4[(size_t)n * (DM / 4) + 256 + t] = v1;
    }
}

extern "C" void kernel_launch(void* const* d_in, const int* in_sizes, int n_in,
                              void* d_out, int out_size, void* d_ws, size_t ws_size,
                              hipStream_t stream) {
    // inputs: 0=q, 1=Wq, 2=Wk, 3=Wv, 4=k_param, 5=v_param, 6=Wo (all fp32)
    const float* Wv     = (const float*)d_in[3];
    const float* vparam = (const float*)d_in[5];
    const float* Wo     = (const float*)d_in[6];
    float* out = (float*)d_out;

    float* part1      = (float*)d_ws;            // 32*2048 floats = 256 KB
    float* r          = part1 + 32 * DM;         // 2048 floats
    unsigned int* cnt = (unsigned int*)(r + DM); // 2 uints

    fused_mha<<<GRID, 256, 0, stream>>>(Wv, vparam, Wo, out, part1, r, cnt);
}

// Round 9
// 27.304 us; speedup vs baseline: 7.2485x; 2.2826x over previous
//
#include <hip/hip_runtime.h>

// N=8192, d_model=2048, h=16, d_k=128.
// softmax over a size-1 axis == 1.0 exactly -> head_out[h,n,:] = v_proj[h,0,:].
// out[n][m] = r[m],  r = vp @ Wo,  vp[h*128+k] = sum_d v_param[d]*Wv[h,d,k].
//
// Software grid barriers are abandoned (R6/R7/R8: 197/116/62 us — poll cost
// always exceeds the ~2 us inter-node gap). Three lean nodes instead:
//  K1 (512 blk): Wv (16 MB, coalesced) -> part1[32][2048]; blocks 0..7 zero r.
//  K2 (512 blk): vp slice from part1 + 64col x 128j Wo tile GEMV
//                (256B full-wave coalesced), LDS reduce, atomicAdd into r.
//  K3 (512 blk): broadcast r to 16 rows/block, float4 stores (64 MB).

#define DM 2048
#define H  16
#define DK 128

// K1: b -> (h = b&15, dseg = b>>4). 256 thr: k = t&127, dh = t>>7.
__global__ __launch_bounds__(256) void k_vp(const float* __restrict__ Wv,
                                            const float* __restrict__ vparam,
                                            float* __restrict__ part1,
                                            float* __restrict__ r) {
    const int b = blockIdx.x;
    const int t = threadIdx.x;
    const int h    = b & 15;
    const int dseg = b >> 4;            // 0..31 (64 d's per block)
    const int k    = t & 127;
    const int dh   = t >> 7;            // 0..1  (32 d's per thread)
    const int d0   = dseg * 64 + dh * 32;
    const float* wp = Wv + ((size_t)h * DM + d0) * DK + k;
    float acc = 0.f;
#pragma unroll
    for (int i = 0; i < 32; ++i) acc += vparam[d0 + i] * wp[(size_t)i * DK];
    __shared__ float ared[128];
    if (dh == 1) ared[k] = acc;
    __syncthreads();
    if (dh == 0) part1[(size_t)dseg * DM + h * DK + k] = acc + ared[k];

    if (b < 8) r[(b << 8) + t] = 0.f;   // accumulator zeroed before K2's atomics
}

// K2: grid (32 ms-slices of 64 cols, 16 jq-chunks of 128 j), 256 thr.
__global__ __launch_bounds__(256) void k_gemv(const float* __restrict__ part1,
                                              const float* __restrict__ Wo,
                                              float* __restrict__ r) {
    const int ms = blockIdx.x;          // cols ms*64 .. +64
    const int jq = blockIdx.y;          // j's  jq*128 .. +128
    const int t  = threadIdx.x;

    __shared__ float vp_s[128];
    if (t < 128) {
        float s = 0.f;
        const float* p = part1 + jq * 128 + t;
#pragma unroll 8
        for (int cc = 0; cc < 32; ++cc) s += p[(size_t)cc * DM];
        vp_s[t] = s;
    }
    __syncthreads();

    const int c  = t & 63;              // 64 consecutive cols -> 256B/wave loads
    const int jg = t >> 6;              // 0..3 (j-groups of 32)
    const float* wo = Wo + (size_t)(jq * 128 + jg * 32) * DM + ms * 64 + c;
    float a2 = 0.f;
#pragma unroll 8
    for (int i = 0; i < 32; ++i) a2 += vp_s[jg * 32 + i] * wo[(size_t)i * DM];

    __shared__ float red[4][65];        // padded: conflict-free
    red[jg][c] = a2;
    __syncthreads();
    if (t < 64) {
        float s = 0.f;
#pragma unroll
        for (int g = 0; g < 4; ++g) s += red[g][t];
        atomicAdd(&r[ms * 64 + t], s);
    }
}

// K3: broadcast r to 16 rows per block, float4 stores.
__global__ __launch_bounds__(256) void k_bcast(const float* __restrict__ r,
                                               float* __restrict__ out) {
    const int b = blockIdx.x;           // 0..511
    const int t = threadIdx.x;
    const float4 v0 = ((const float4*)r)[t];
    const float4 v1 = ((const float4*)r)[256 + t];
    float4* o4 = (float4*)out + (size_t)b * 16 * (DM / 4);
#pragma unroll
    for (int n = 0; n < 16; ++n) {
        o4[(size_t)n * (DM / 4) + t]       = v0;
        o4[(size_t)n * (DM / 4) + 256 + t] = v1;
    }
}

extern "C" void kernel_launch(void* const* d_in, const int* in_sizes, int n_in,
                              void* d_out, int out_size, void* d_ws, size_t ws_size,
                              hipStream_t stream) {
    // inputs: 0=q, 1=Wq, 2=Wk, 3=Wv, 4=k_param, 5=v_param, 6=Wo (all fp32)
    const float* Wv     = (const float*)d_in[3];
    const float* vparam = (const float*)d_in[5];
    const float* Wo     = (const float*)d_in[6];
    float* out = (float*)d_out;

    float* part1 = (float*)d_ws;        // 32*2048 floats = 256 KB
    float* r     = part1 + 32 * DM;     // 2048 floats

    k_vp   <<<512,          256, 0, stream>>>(Wv, vparam, part1, r);
    k_gemv <<<dim3(32, 16), 256, 0, stream>>>(part1, Wo, r);
    k_bcast<<<512,          256, 0, stream>>>(r, out);
}

// Round 10
// 26.306 us; speedup vs baseline: 7.5236x; 1.0380x over previous
//
#include <hip/hip_runtime.h>

// N=8192, d_model=2048, h=16, d_k=128.
// softmax over a size-1 axis == 1.0 exactly -> head_out[h,n,:] = v_proj[h,0,:].
// out[n][m] = r[m],  r = vp @ Wo,  vp[h*128+k] = sum_d v_param[d]*Wv[h,d,k].
//
// R9 lesson: read kernels were LATENCY-bound (scalar loads, ~6 in flight,
// ~12 KB/CU outstanding vs ~24 KB needed). This version: float4 loads with
// 8 independent streams per thread -> ~64 KB/CU outstanding, BW-bound.
//  K1 (512 blk): Wv (16 MB) -> part1[32][2048]; blocks 0..7 zero r.
//  K2 (32x16 blk): vp slice from part1, float4 GEMV vs Wo, atomicAdd r.
//  K3 (512 blk): broadcast r, float4 stores (64 MB) — already at BW.

#define DM 2048
#define H  16
#define DK 128

__device__ __forceinline__ void fma4(float4& a, float s, const float4& w) {
    a.x += s * w.x; a.y += s * w.y; a.z += s * w.z; a.w += s * w.w;
}

// K1: b -> (h = b&15, ds = b>>4 in [0,32)), d-range ds*64..+64. 256 thr:
// k4 = t&31 (k = 4*k4..+3), dg = t>>5 in [0,8): 8 independent float4 loads.
__global__ __launch_bounds__(256) void k_vp(const float* __restrict__ Wv,
                                            const float* __restrict__ vparam,
                                            float* __restrict__ part1,
                                            float* __restrict__ r) {
    const int b  = blockIdx.x;
    const int t  = threadIdx.x;
    const int h  = b & 15;
    const int ds = b >> 4;
    const int k4 = t & 31;
    const int dg = t >> 5;
    const int d0 = ds * 64 + dg * 8;

    const float* base = Wv + ((size_t)h * DM + d0) * DK + 4 * k4;
    float4 acc = {0.f, 0.f, 0.f, 0.f};
#pragma unroll
    for (int i = 0; i < 8; ++i) {
        const float4 w4 = *(const float4*)(base + (size_t)i * DK);
        fma4(acc, vparam[d0 + i], w4);
    }

    __shared__ float4 sred[8][32];
    sred[dg][k4] = acc;
    __syncthreads();
    if (t < 32) {
        float4 s = sred[0][t];
#pragma unroll
        for (int g = 1; g < 8; ++g) {
            const float4 v = sred[g][t];
            s.x += v.x; s.y += v.y; s.z += v.z; s.w += v.w;
        }
        *(float4*)(part1 + (size_t)ds * DM + h * DK + 4 * t) = s;
    }

    if (b < 8) r[(b << 8) + t] = 0.f;   // zeroed before K2's atomics (node order)
}

// K2: grid (32 ms-slices of 64 cols, 16 jq-chunks of 128 j), 256 thr.
__global__ __launch_bounds__(256) void k_gemv(const float* __restrict__ part1,
                                              const float* __restrict__ Wo,
                                              float* __restrict__ r) {
    const int ms = blockIdx.x;          // cols ms*64 .. +64
    const int jq = blockIdx.y;          // j's  jq*128 .. +128
    const int t  = threadIdx.x;

    // stage vp slice: vp_s[jl] = sum over 32 partials
    __shared__ float vph[2][128];
    __shared__ float vp_s[128];
    {
        const int jl = t & 127;
        const int hf = t >> 7;          // 0..1, 16 partials each
        const float* p = part1 + (size_t)(hf * 16) * DM + jq * 128 + jl;
        float s = 0.f;
#pragma unroll
        for (int c = 0; c < 16; ++c) s += p[(size_t)c * DM];
        vph[hf][jl] = s;
    }
    __syncthreads();
    if (t < 128) vp_s[t] = vph[0][t] + vph[1][t];
    __syncthreads();

    // float4 GEMV: m4 = t&15 (4 cols), jg = t>>4 in [0,16): 8 indep loads
    const int m4 = t & 15;
    const int jg = t >> 4;
    const float* wo = Wo + (size_t)(jq * 128 + jg * 8) * DM + ms * 64 + 4 * m4;
    float4 acc = {0.f, 0.f, 0.f, 0.f};
#pragma unroll
    for (int i = 0; i < 8; ++i) {
        const float4 w4 = *(const float4*)(wo + (size_t)i * DM);
        fma4(acc, vp_s[jg * 8 + i], w4);
    }

    __shared__ float4 red4[16][16];
    red4[jg][m4] = acc;
    __syncthreads();
    if (t < 64) {
        const int mm = t & 15;          // col group
        const int cc = t >> 4;          // component
        float s = 0.f;
#pragma unroll
        for (int g = 0; g < 16; ++g) s += ((const float*)&red4[g][mm])[cc];
        atomicAdd(&r[ms * 64 + 4 * mm + cc], s);
    }
}

// K3: broadcast r to 16 rows per block, float4 stores (at BW already).
__global__ __launch_bounds__(256) void k_bcast(const float* __restrict__ r,
                                               float* __restrict__ out) {
    const int b = blockIdx.x;           // 0..511
    const int t = threadIdx.x;
    const float4 v0 = ((const float4*)r)[t];
    const float4 v1 = ((const float4*)r)[256 + t];
    float4* o4 = (float4*)out + (size_t)b * 16 * (DM / 4);
#pragma unroll
    for (int n = 0; n < 16; ++n) {
        o4[(size_t)n * (DM / 4) + t]       = v0;
        o4[(size_t)n * (DM / 4) + 256 + t] = v1;
    }
}

extern "C" void kernel_launch(void* const* d_in, const int* in_sizes, int n_in,
                              void* d_out, int out_size, void* d_ws, size_t ws_size,
                              hipStream_t stream) {
    // inputs: 0=q, 1=Wq, 2=Wk, 3=Wv, 4=k_param, 5=v_param, 6=Wo (all fp32)
    const float* Wv     = (const float*)d_in[3];
    const float* vparam = (const float*)d_in[5];
    const float* Wo     = (const float*)d_in[6];
    float* out = (float*)d_out;

    float* part1 = (float*)d_ws;        // 32*2048 floats = 256 KB
    float* r     = part1 + 32 * DM;     // 2048 floats

    k_vp   <<<512,          256, 0, stream>>>(Wv, vparam, part1, r);
    k_gemv <<<dim3(32, 16), 256, 0, stream>>>(part1, Wo, r);
    k_bcast<<<512,          256, 0, stream>>>(r, out);
}